// Round 1
// 673.728 us; speedup vs baseline: 1.0336x; 1.0336x over previous
//
#include <hip/hip_runtime.h>
#include <hip/hip_bf16.h>

#define FEATURE_DIM 512
#define CLASS_NUM   100000
#define BATCH       512
#define NTILE       128
#define NBLK        782      // ceil(100000/128)
#define SCALE       30.0f
#define MARGIN      0.5f

typedef unsigned short u16;
typedef __attribute__((ext_vector_type(8))) short bf16x8;
typedef __attribute__((ext_vector_type(4))) float f32x4;

__device__ __forceinline__ u16 f32_to_bf16(float f) {
    unsigned int x = __builtin_bit_cast(unsigned int, f);
    unsigned int r = (x + 0x7fffu + ((x >> 16) & 1u)) >> 16;
    return (u16)r;
}

#define GLL(g, l) __builtin_amdgcn_global_load_lds( \
    (const __attribute__((address_space(1))) void*)(g), \
    (__attribute__((address_space(3))) void*)(l), 16, 0, 0)

// ---------------------------------------------------------------------------
// Normalize rows of src [R][512] fp32 -> dst [R][512] bf16, one wave/row.
// Per-block sum of norms -> partials[block].  (Used for feat only now.)
// ---------------------------------------------------------------------------
__global__ __launch_bounds__(256) void normalize_rows(
    const float* __restrict__ src, u16* __restrict__ dst,
    float* __restrict__ partials, int R)
{
    const int tid  = threadIdx.x;
    const int wid  = tid >> 6;
    const int lane = tid & 63;
    const int row  = blockIdx.x * 4 + wid;
    __shared__ float s_norm[4];

    float norm = 0.0f;
    u16* drow = dst + (size_t)row * FEATURE_DIM;
    if (row < R) {
        const float4* p = (const float4*)(src + (size_t)row * FEATURE_DIM);
        float4 a = p[lane];
        float4 b = p[lane + 64];
        float ss = a.x*a.x + a.y*a.y + a.z*a.z + a.w*a.w
                 + b.x*b.x + b.y*b.y + b.z*b.z + b.w*b.w;
        #pragma unroll
        for (int o = 32; o > 0; o >>= 1) ss += __shfl_xor(ss, o, 64);
        norm = sqrtf(ss);
        float inv = 1.0f / norm;
        ushort4 pa, pb;
        pa.x = f32_to_bf16(a.x * inv); pa.y = f32_to_bf16(a.y * inv);
        pa.z = f32_to_bf16(a.z * inv); pa.w = f32_to_bf16(a.w * inv);
        pb.x = f32_to_bf16(b.x * inv); pb.y = f32_to_bf16(b.y * inv);
        pb.z = f32_to_bf16(b.z * inv); pb.w = f32_to_bf16(b.w * inv);
        ushort4* q = (ushort4*)drow;
        q[lane]      = pa;
        q[lane + 64] = pb;
    }
    if (lane == 0) s_norm[wid] = norm;
    __syncthreads();
    if (tid == 0)
        partials[blockIdx.x] = s_norm[0] + s_norm[1] + s_norm[2] + s_norm[3];
}

// ---------------------------------------------------------------------------
// Fused GEMM: reads raw fp32 weights ONCE, converts to bf16 while staging,
// accumulates per-class-row sum-of-squares on the fly, divides by |w| in the
// epilogue.  cos[m][n] = (nfeat[m]·w[n]) / |w[n]|.
// Block tile 512(M) x 128(N), BK=32, 512 threads = 8 waves (4M x 2N),
// each wave 128x64 via 8x4 mfma_f32_16x16x32_bf16.
// Also writes per-block sum of |w[n]| -> pw[block] for avg_w_norm.
// ---------------------------------------------------------------------------
__global__ __launch_bounds__(512, 2) void gemm_fused(
    const u16*  __restrict__ A,    // nfeat bf16 [512][512]
    const float* __restrict__ W,   // raw weights fp32 [100000][512]
    float* __restrict__ cosO, float* __restrict__ logO,
    float* __restrict__ pw)
{
    __shared__ u16 As[512 * 32];      // 32 KiB
    __shared__ u16 Bs[128 * 32];      // 8 KiB
    __shared__ float s_inv[128];
    __shared__ float s_red[8];

    const int tid  = threadIdx.x;
    const int n0   = blockIdx.x * NTILE;
    const int wid  = tid >> 6;
    const int lane = tid & 63;
    const int wm   = (wid & 3) << 7;   // wave m offset: 0,128,256,384
    const int wn   = (wid >> 2) << 6;  // wave n offset: 0,64
    const int quad = lane >> 4;
    const int l15  = lane & 15;

    f32x4 acc[8][4];
    #pragma unroll
    for (int i = 0; i < 8; ++i)
        #pragma unroll
        for (int j = 0; j < 4; ++j)
            acc[i][j] = (f32x4){0.f, 0.f, 0.f, 0.f};

    const int srow = tid >> 2;         // 0..127
    const int scol = (tid & 3) * 8;    // 0,8,16,24
    const u16* gA = A + (size_t)srow * FEATURE_DIM + scol;
    u16* lA = As + (size_t)tid * 8;

    const int   brow = n0 + srow;
    const bool  bval = brow < CLASS_NUM;
    const float* gW  = W + (size_t)brow * FEATURE_DIM + scol;

    float ssq = 0.0f;

    for (int k0 = 0; k0 < FEATURE_DIM; k0 += 32) {
        // A staging: global -> LDS direct (4 x 16B per thread covers 512 rows)
        GLL(gA + k0,                       lA);
        GLL(gA + k0 + 128 * FEATURE_DIM,  lA + 4096);
        GLL(gA + k0 + 256 * FEATURE_DIM,  lA + 8192);
        GLL(gA + k0 + 384 * FEATURE_DIM,  lA + 12288);

        // B staging: fp32 regs -> ssq accumulate -> bf16 -> LDS
        float4 b0 = {0.f, 0.f, 0.f, 0.f};
        float4 b1 = {0.f, 0.f, 0.f, 0.f};
        if (bval) {
            const float4* p = (const float4*)(gW + k0);
            b0 = p[0];
            b1 = p[1];
        }
        ssq += b0.x*b0.x + b0.y*b0.y + b0.z*b0.z + b0.w*b0.w
             + b1.x*b1.x + b1.y*b1.y + b1.z*b1.z + b1.w*b1.w;
        bf16x8 bb;
        bb[0] = (short)f32_to_bf16(b0.x); bb[1] = (short)f32_to_bf16(b0.y);
        bb[2] = (short)f32_to_bf16(b0.z); bb[3] = (short)f32_to_bf16(b0.w);
        bb[4] = (short)f32_to_bf16(b1.x); bb[5] = (short)f32_to_bf16(b1.y);
        bb[6] = (short)f32_to_bf16(b1.z); bb[7] = (short)f32_to_bf16(b1.w);
        *(bf16x8*)(Bs + (size_t)tid * 8) = bb;

        __syncthreads();   // drains vmcnt (GLL) + lgkmcnt (ds_write)

        bf16x8 af[8], bfr[4];
        #pragma unroll
        for (int mi = 0; mi < 8; ++mi)
            af[mi] = *(const bf16x8*)(As + (wm + mi * 16 + l15) * 32 + quad * 8);
        #pragma unroll
        for (int ni = 0; ni < 4; ++ni)
            bfr[ni] = *(const bf16x8*)(Bs + (wn + ni * 16 + l15) * 32 + quad * 8);

        #pragma unroll
        for (int mi = 0; mi < 8; ++mi)
            #pragma unroll
            for (int ni = 0; ni < 4; ++ni)
                acc[mi][ni] = __builtin_amdgcn_mfma_f32_16x16x32_bf16(
                    af[mi], bfr[ni], acc[mi][ni], 0, 0, 0);

        __syncthreads();   // LDS reads done before next stage overwrites
    }

    // Finalize norms: 4 staging threads per row each hold 128-elem partial.
    ssq += __shfl_xor(ssq, 1, 64);
    ssq += __shfl_xor(ssq, 2, 64);
    float norm = bval ? sqrtf(ssq) : 0.0f;
    if ((tid & 3) == 0)
        s_inv[srow] = bval ? (1.0f / norm) : 0.0f;

    float nv = ((tid & 3) == 0) ? norm : 0.0f;
    #pragma unroll
    for (int o = 32; o > 0; o >>= 1) nv += __shfl_xor(nv, o, 64);
    if (lane == 0) s_red[wid] = nv;
    __syncthreads();   // also publishes s_inv for the epilogue
    if (tid == 0) {
        float t = 0.f;
        #pragma unroll
        for (int i = 0; i < 8; ++i) t += s_red[i];
        pw[blockIdx.x] = t;
    }

    // Epilogue. C/D layout: col = lane&15, row = quad*4 + reg.
    #pragma unroll
    for (int ni = 0; ni < 4; ++ni) {
        int c  = wn + ni * 16 + l15;
        int gc = n0 + c;
        if (gc < CLASS_NUM) {
            float invc = s_inv[c];
            #pragma unroll
            for (int mi = 0; mi < 8; ++mi) {
                int gr0 = wm + mi * 16 + quad * 4;
                f32x4 v = acc[mi][ni];
                #pragma unroll
                for (int r = 0; r < 4; ++r) {
                    float cv = v[r] * invc;
                    size_t idx = (size_t)(gr0 + r) * CLASS_NUM + gc;
                    cosO[idx] = cv;
                    logO[idx] = SCALE * cv;
                }
            }
        }
    }
}

// ---------------------------------------------------------------------------
// Stats + margin fixup. One block, 512 threads (one per batch row).
// ---------------------------------------------------------------------------
__global__ __launch_bounds__(512) void stats_kernel(
    const float* __restrict__ cosO, float* __restrict__ logO,
    const int* __restrict__ label,
    const float* __restrict__ pw, int npw,
    const float* __restrict__ px, int npx,
    float* __restrict__ scal)
{
    const int tid  = threadIdx.x;
    const int wid  = tid >> 6;
    const int lane = tid & 63;

    __shared__ float r_sum[8], r_min[8], r_max[8], r_w[8], r_x[8], r_var[8];
    __shared__ float s_avg;

    int lab = label[tid];
    lab = max(0, min(CLASS_NUM - 1, lab));
    float x = cosO[(size_t)tid * CLASS_NUM + lab];

    const float cosm = 0.8775825618903728f;   // cos(0.5)
    const float sinm = 0.4794255386042030f;   // sin(0.5)
    float lg;
    if (x > -cosm)
        lg = SCALE * (x * cosm - sinm * sqrtf(fmaxf(0.f, 1.f - x * x)));
    else
        lg = SCALE * (x - MARGIN * sinm);
    logO[(size_t)tid * CLASS_NUM + lab] = lg;

    float xc = fminf(1.f, fmaxf(-1.f, x));
    float theta = acosf(xc) * 57.29577951308232f;   // deg

    float sw = 0.f;
    for (int i = tid; i < npw; i += 512) sw += pw[i];
    float sx = (tid < npx) ? px[tid] : 0.f;

    float s = theta, mn = theta, mx = theta;
    #pragma unroll
    for (int o = 32; o > 0; o >>= 1) {
        s  += __shfl_xor(s, o, 64);
        mn  = fminf(mn, __shfl_xor(mn, o, 64));
        mx  = fmaxf(mx, __shfl_xor(mx, o, 64));
        sw += __shfl_xor(sw, o, 64);
        sx += __shfl_xor(sx, o, 64);
    }
    if (lane == 0) {
        r_sum[wid] = s; r_min[wid] = mn; r_max[wid] = mx;
        r_w[wid] = sw; r_x[wid] = sx;
    }
    __syncthreads();
    if (tid == 0) {
        float ts = 0.f, tmn = r_min[0], tmx = r_max[0], tw = 0.f, tx = 0.f;
        #pragma unroll
        for (int i = 0; i < 8; ++i) {
            ts += r_sum[i];
            tmn = fminf(tmn, r_min[i]);
            tmx = fmaxf(tmx, r_max[i]);
            tw += r_w[i];
            tx += r_x[i];
        }
        float avg = ts * (1.0f / BATCH);
        s_avg = avg;
        scal[0] = avg;                       // avg_theta
        scal[1] = tmn;                       // min_theta
        scal[2] = tmx;                       // max_theta
        scal[4] = tw * (1.0f / CLASS_NUM);   // avg_w_norm
        scal[5] = tx * (1.0f / BATCH);       // avg_x_norm
    }
    __syncthreads();
    float d = theta - s_avg;
    float v = d * d;
    #pragma unroll
    for (int o = 32; o > 0; o >>= 1) v += __shfl_xor(v, o, 64);
    if (lane == 0) r_var[wid] = v;
    __syncthreads();
    if (tid == 0) {
        float tv = 0.f;
        #pragma unroll
        for (int i = 0; i < 8; ++i) tv += r_var[i];
        scal[3] = sqrtf(tv / (BATCH - 1));   // stdv_theta
    }
}

// ---------------------------------------------------------------------------
extern "C" void kernel_launch(void* const* d_in, const int* in_sizes, int n_in,
                              void* d_out, int out_size, void* d_ws, size_t ws_size,
                              hipStream_t stream)
{
    const float* feat    = (const float*)d_in[0];
    const float* weights = (const float*)d_in[1];
    const int*   label   = (const int*)d_in[2];

    float* out  = (float*)d_out;
    float* cosO = out;
    float* logO = out + (size_t)BATCH * CLASS_NUM;
    float* scal = out + 2 * (size_t)BATCH * CLASS_NUM;

    // workspace layout: nfeat bf16 + px[128] + pw[782]
    const size_t nfeat_bytes = (size_t)BATCH * FEATURE_DIM * sizeof(u16);   // 512 KiB
    const size_t need = nfeat_bytes + (128 + NBLK) * sizeof(float);
    if (ws_size < need) return;  // loud failure rather than OOB corruption

    char*  ws    = (char*)d_ws;
    u16*   nfeat = (u16*)ws;
    float* px    = (float*)(ws + nfeat_bytes);
    float* pw    = px + 128;

    normalize_rows<<<BATCH / 4, 256, 0, stream>>>(feat, nfeat, px, BATCH);

    gemm_fused<<<NBLK, 512, 0, stream>>>(nfeat, weights, cosO, logO, pw);

    stats_kernel<<<1, 512, 0, stream>>>(cosO, logO, label,
                                        pw, NBLK, px, BATCH / 4, scal);
}

// Round 2
// 644.902 us; speedup vs baseline: 1.0798x; 1.0447x over previous
//
#include <hip/hip_runtime.h>
#include <hip/hip_bf16.h>

#define FEATURE_DIM 512
#define CLASS_NUM   100000
#define BATCH       512
#define NTILE       128
#define NBLK        782      // ceil(100000/128)
#define SCALE       30.0f
#define MARGIN      0.5f

typedef unsigned short u16;
typedef __attribute__((ext_vector_type(8))) short bf16x8;
typedef __attribute__((ext_vector_type(4))) float f32x4;

__device__ __forceinline__ u16 f32_to_bf16(float f) {
    unsigned int x = __builtin_bit_cast(unsigned int, f);
    unsigned int r = (x + 0x7fffu + ((x >> 16) & 1u)) >> 16;
    return (u16)r;
}

#define GLL(g, l) __builtin_amdgcn_global_load_lds( \
    (const __attribute__((address_space(1))) void*)(g), \
    (__attribute__((address_space(3))) void*)(l), 16, 0, 0)

// ---------------------------------------------------------------------------
// Normalize rows of src [R][512] fp32 -> dst [R][512] bf16, one wave/row.
// Per-block sum of norms -> partials[block].  (feat only)
// ---------------------------------------------------------------------------
__global__ __launch_bounds__(256) void normalize_rows(
    const float* __restrict__ src, u16* __restrict__ dst,
    float* __restrict__ partials, int R)
{
    const int tid  = threadIdx.x;
    const int wid  = tid >> 6;
    const int lane = tid & 63;
    const int row  = blockIdx.x * 4 + wid;
    __shared__ float s_norm[4];

    float norm = 0.0f;
    u16* drow = dst + (size_t)row * FEATURE_DIM;
    if (row < R) {
        const float4* p = (const float4*)(src + (size_t)row * FEATURE_DIM);
        float4 a = p[lane];
        float4 b = p[lane + 64];
        float ss = a.x*a.x + a.y*a.y + a.z*a.z + a.w*a.w
                 + b.x*b.x + b.y*b.y + b.z*b.z + b.w*b.w;
        #pragma unroll
        for (int o = 32; o > 0; o >>= 1) ss += __shfl_xor(ss, o, 64);
        norm = sqrtf(ss);
        float inv = 1.0f / norm;
        ushort4 pa, pb;
        pa.x = f32_to_bf16(a.x * inv); pa.y = f32_to_bf16(a.y * inv);
        pa.z = f32_to_bf16(a.z * inv); pa.w = f32_to_bf16(a.w * inv);
        pb.x = f32_to_bf16(b.x * inv); pb.y = f32_to_bf16(b.y * inv);
        pb.z = f32_to_bf16(b.z * inv); pb.w = f32_to_bf16(b.w * inv);
        ushort4* q = (ushort4*)drow;
        q[lane]      = pa;
        q[lane + 64] = pb;
    }
    if (lane == 0) s_norm[wid] = norm;
    __syncthreads();
    if (tid == 0)
        partials[blockIdx.x] = s_norm[0] + s_norm[1] + s_norm[2] + s_norm[3];
}

// ---------------------------------------------------------------------------
// Fused GEMM: reads raw fp32 weights, converts to bf16 while staging,
// accumulates per-class-row sum-of-squares on the fly, divides by |w| in the
// epilogue.  cos[m][n] = (nfeat[m]·w[n]) / |w[n]|.
//
// Block tile 256(M) x 128(N), BK=32, 512 threads = 8 waves (4M x 2N),
// each wave 64x64 via 4x4 mfma_f32_16x16x32_bf16 -> acc = 64 VGPRs,
// fits the 128-reg cap of __launch_bounds__(512,2) (no spill; round-1's
// acc[8][4]=128 VGPRs spilled under the same cap and cost ~25us).
//
// Grid is (2, 782) with M fastest, so the two M-tiles sharing a W panel
// dispatch back-to-back and the second read of the fp32 W tile hits L2/L3.
// Block x==0 also writes per-N-block sum of |w[n]| -> pw[blockIdx.y].
// ---------------------------------------------------------------------------
__global__ __launch_bounds__(512, 2) void gemm_fused(
    const u16*  __restrict__ A,    // nfeat bf16 [512][512]
    const float* __restrict__ W,   // raw weights fp32 [100000][512]
    float* __restrict__ cosO, float* __restrict__ logO,
    float* __restrict__ pw)
{
    __shared__ u16 As[256 * 32];      // 16 KiB
    __shared__ u16 Bs[128 * 32];      // 8 KiB
    __shared__ float s_inv[128];
    __shared__ float s_red[8];

    const int tid  = threadIdx.x;
    const int m0   = blockIdx.x * 256;
    const int n0   = blockIdx.y * NTILE;
    const int wid  = tid >> 6;
    const int lane = tid & 63;
    const int wm   = (wid & 3) << 6;   // wave m offset: 0,64,128,192
    const int wn   = (wid >> 2) << 6;  // wave n offset: 0,64
    const int quad = lane >> 4;
    const int l15  = lane & 15;

    f32x4 acc[4][4];
    #pragma unroll
    for (int i = 0; i < 4; ++i)
        #pragma unroll
        for (int j = 0; j < 4; ++j)
            acc[i][j] = (f32x4){0.f, 0.f, 0.f, 0.f};

    const int srow = tid >> 2;         // 0..127
    const int scol = (tid & 3) * 8;    // 0,8,16,24
    const u16* gA0 = A + (size_t)(m0 + srow) * FEATURE_DIM + scol;
    u16* lA0 = As + (size_t)tid * 8;
    u16* lA1 = As + (size_t)(512 + tid) * 8;

    const int   brow = n0 + srow;
    const bool  bval = brow < CLASS_NUM;
    const float* gW  = W + (size_t)brow * FEATURE_DIM + scol;

    float ssq = 0.0f;

    for (int k0 = 0; k0 < FEATURE_DIM; k0 += 32) {
        // A staging: global -> LDS direct (2 x 16B per thread covers 256 rows)
        GLL(gA0 + k0,                      lA0);
        GLL(gA0 + k0 + 128 * FEATURE_DIM, lA1);

        // B staging: fp32 regs -> ssq accumulate -> bf16 -> LDS
        float4 b0 = {0.f, 0.f, 0.f, 0.f};
        float4 b1 = {0.f, 0.f, 0.f, 0.f};
        if (bval) {
            const float4* p = (const float4*)(gW + k0);
            b0 = p[0];
            b1 = p[1];
        }
        ssq += b0.x*b0.x + b0.y*b0.y + b0.z*b0.z + b0.w*b0.w
             + b1.x*b1.x + b1.y*b1.y + b1.z*b1.z + b1.w*b1.w;
        bf16x8 bb;
        bb[0] = (short)f32_to_bf16(b0.x); bb[1] = (short)f32_to_bf16(b0.y);
        bb[2] = (short)f32_to_bf16(b0.z); bb[3] = (short)f32_to_bf16(b0.w);
        bb[4] = (short)f32_to_bf16(b1.x); bb[5] = (short)f32_to_bf16(b1.y);
        bb[6] = (short)f32_to_bf16(b1.z); bb[7] = (short)f32_to_bf16(b1.w);
        *(bf16x8*)(Bs + (size_t)tid * 8) = bb;

        __syncthreads();   // drains vmcnt (GLL) + lgkmcnt (ds_write)

        bf16x8 bfr[4];
        #pragma unroll
        for (int ni = 0; ni < 4; ++ni)
            bfr[ni] = *(const bf16x8*)(Bs + (wn + ni * 16 + l15) * 32 + quad * 8);

        // af loaded per-mi to keep peak VGPR liveness under the 128 cap
        #pragma unroll
        for (int mi = 0; mi < 4; ++mi) {
            bf16x8 af = *(const bf16x8*)(As + (wm + mi * 16 + l15) * 32 + quad * 8);
            #pragma unroll
            for (int ni = 0; ni < 4; ++ni)
                acc[mi][ni] = __builtin_amdgcn_mfma_f32_16x16x32_bf16(
                    af, bfr[ni], acc[mi][ni], 0, 0, 0);
        }

        __syncthreads();   // LDS reads done before next stage overwrites
    }

    // Finalize norms: 4 staging threads per row each hold a 128-elem partial.
    ssq += __shfl_xor(ssq, 1, 64);
    ssq += __shfl_xor(ssq, 2, 64);
    float norm = bval ? sqrtf(ssq) : 0.0f;
    if ((tid & 3) == 0)
        s_inv[srow] = bval ? (1.0f / norm) : 0.0f;

    if (blockIdx.x == 0) {
        float nv = ((tid & 3) == 0) ? norm : 0.0f;
        #pragma unroll
        for (int o = 32; o > 0; o >>= 1) nv += __shfl_xor(nv, o, 64);
        if (lane == 0) s_red[wid] = nv;
    }
    __syncthreads();   // publishes s_inv (and s_red) for the epilogue
    if (blockIdx.x == 0 && tid == 0) {
        float t = 0.f;
        #pragma unroll
        for (int i = 0; i < 8; ++i) t += s_red[i];
        pw[blockIdx.y] = t;
    }

    // Epilogue. C/D layout: col = lane&15, row = quad*4 + reg.
    #pragma unroll
    for (int ni = 0; ni < 4; ++ni) {
        int c  = wn + ni * 16 + l15;
        int gc = n0 + c;
        if (gc < CLASS_NUM) {
            float invc = s_inv[c];
            #pragma unroll
            for (int mi = 0; mi < 4; ++mi) {
                int gr0 = m0 + wm + mi * 16 + quad * 4;
                f32x4 v = acc[mi][ni];
                #pragma unroll
                for (int r = 0; r < 4; ++r) {
                    float cv = v[r] * invc;
                    size_t idx = (size_t)(gr0 + r) * CLASS_NUM + gc;
                    cosO[idx] = cv;
                    logO[idx] = SCALE * cv;
                }
            }
        }
    }
}

// ---------------------------------------------------------------------------
// Stats + margin fixup. One block, 512 threads (one per batch row).
// ---------------------------------------------------------------------------
__global__ __launch_bounds__(512) void stats_kernel(
    const float* __restrict__ cosO, float* __restrict__ logO,
    const int* __restrict__ label,
    const float* __restrict__ pw, int npw,
    const float* __restrict__ px, int npx,
    float* __restrict__ scal)
{
    const int tid  = threadIdx.x;
    const int wid  = tid >> 6;
    const int lane = tid & 63;

    __shared__ float r_sum[8], r_min[8], r_max[8], r_w[8], r_x[8], r_var[8];
    __shared__ float s_avg;

    int lab = label[tid];
    lab = max(0, min(CLASS_NUM - 1, lab));
    float x = cosO[(size_t)tid * CLASS_NUM + lab];

    const float cosm = 0.8775825618903728f;   // cos(0.5)
    const float sinm = 0.4794255386042030f;   // sin(0.5)
    float lg;
    if (x > -cosm)
        lg = SCALE * (x * cosm - sinm * sqrtf(fmaxf(0.f, 1.f - x * x)));
    else
        lg = SCALE * (x - MARGIN * sinm);
    logO[(size_t)tid * CLASS_NUM + lab] = lg;

    float xc = fminf(1.f, fmaxf(-1.f, x));
    float theta = acosf(xc) * 57.29577951308232f;   // deg

    float sw = 0.f;
    for (int i = tid; i < npw; i += 512) sw += pw[i];
    float sx = (tid < npx) ? px[tid] : 0.f;

    float s = theta, mn = theta, mx = theta;
    #pragma unroll
    for (int o = 32; o > 0; o >>= 1) {
        s  += __shfl_xor(s, o, 64);
        mn  = fminf(mn, __shfl_xor(mn, o, 64));
        mx  = fmaxf(mx, __shfl_xor(mx, o, 64));
        sw += __shfl_xor(sw, o, 64);
        sx += __shfl_xor(sx, o, 64);
    }
    if (lane == 0) {
        r_sum[wid] = s; r_min[wid] = mn; r_max[wid] = mx;
        r_w[wid] = sw; r_x[wid] = sx;
    }
    __syncthreads();
    if (tid == 0) {
        float ts = 0.f, tmn = r_min[0], tmx = r_max[0], tw = 0.f, tx = 0.f;
        #pragma unroll
        for (int i = 0; i < 8; ++i) {
            ts += r_sum[i];
            tmn = fminf(tmn, r_min[i]);
            tmx = fmaxf(tmx, r_max[i]);
            tw += r_w[i];
            tx += r_x[i];
        }
        float avg = ts * (1.0f / BATCH);
        s_avg = avg;
        scal[0] = avg;                       // avg_theta
        scal[1] = tmn;                       // min_theta
        scal[2] = tmx;                       // max_theta
        scal[4] = tw * (1.0f / CLASS_NUM);   // avg_w_norm
        scal[5] = tx * (1.0f / BATCH);       // avg_x_norm
    }
    __syncthreads();
    float d = theta - s_avg;
    float v = d * d;
    #pragma unroll
    for (int o = 32; o > 0; o >>= 1) v += __shfl_xor(v, o, 64);
    if (lane == 0) r_var[wid] = v;
    __syncthreads();
    if (tid == 0) {
        float tv = 0.f;
        #pragma unroll
        for (int i = 0; i < 8; ++i) tv += r_var[i];
        scal[3] = sqrtf(tv / (BATCH - 1));   // stdv_theta
    }
}

// ---------------------------------------------------------------------------
extern "C" void kernel_launch(void* const* d_in, const int* in_sizes, int n_in,
                              void* d_out, int out_size, void* d_ws, size_t ws_size,
                              hipStream_t stream)
{
    const float* feat    = (const float*)d_in[0];
    const float* weights = (const float*)d_in[1];
    const int*   label   = (const int*)d_in[2];

    float* out  = (float*)d_out;
    float* cosO = out;
    float* logO = out + (size_t)BATCH * CLASS_NUM;
    float* scal = out + 2 * (size_t)BATCH * CLASS_NUM;

    // workspace layout: nfeat bf16 + px[128] + pw[782]
    const size_t nfeat_bytes = (size_t)BATCH * FEATURE_DIM * sizeof(u16);   // 512 KiB
    const size_t need = nfeat_bytes + (128 + NBLK) * sizeof(float);
    if (ws_size < need) return;  // loud failure rather than OOB corruption

    char*  ws    = (char*)d_ws;
    u16*   nfeat = (u16*)ws;
    float* px    = (float*)(ws + nfeat_bytes);
    float* pw    = px + 128;

    normalize_rows<<<BATCH / 4, 256, 0, stream>>>(feat, nfeat, px, BATCH);

    dim3 grid(2, NBLK);   // M fastest: paired blocks share the W panel via L2/L3
    gemm_fused<<<grid, 512, 0, stream>>>(nfeat, weights, cosO, logO, pw);

    stats_kernel<<<1, 512, 0, stream>>>(cosO, logO, label,
                                        pw, NBLK, px, BATCH / 4, scal);
}